// Round 10
// baseline (196.190 us; speedup 1.0000x reference)
//
#include <hip/hip_runtime.h>
#include <hip/hip_bf16.h>

#define T_NUM_TABLES 26
#define T_NUM_ROWS 50000
#define T_WIDTH 128
#define T_BATCH 4096
#define T_NNZ 20
#define T_NUM_NUM 13
#define T_DE (T_NUM_TABLES * T_WIDTH) /* 3328 = 64*52 */

typedef __attribute__((ext_vector_type(4))) float f32x4;
typedef __attribute__((ext_vector_type(8))) short bf16x8;

// ================= fused pool + prep =================
#define PJ_POOL (512 * T_NUM_TABLES)         /* 13312 */
#define PJ_WT (PJ_POOL + 1664 + 128 + 32)    /* 15136 */
#define PJ_TOTAL (PJ_WT + T_BATCH)           /* 19232 */

__global__ void poolprep_v10(const float* __restrict__ tables,
                             const int* __restrict__ cat,
                             const float* __restrict__ W1, const float* __restrict__ W2,
                             const float* __restrict__ W3, const float* __restrict__ b1,
                             const float* __restrict__ b4, const float* __restrict__ num,
                             __hip_bfloat16* __restrict__ xh,
                             __hip_bfloat16* __restrict__ w1t, __hip_bfloat16* __restrict__ w2t,
                             __hip_bfloat16* __restrict__ w3t, float* __restrict__ c0,
                             float* __restrict__ out) {
  __shared__ int sidx[8][T_NNZ];
  __shared__ float tile[32][33];
  __shared__ float snum[T_NUM_NUM];
  const int bid = blockIdx.x;

  if (bid < PJ_POOL) { // ---------------- pool: float4 gathers, table-major
    const int g = bid & 511;
    const int t = bid >> 9;
    const int b0 = g * 8;
    const int tx = threadIdx.x & 31;
    const int ty = threadIdx.x >> 5;
    if (threadIdx.x < 8 * T_NNZ) {
      int y = threadIdx.x / T_NNZ, j = threadIdx.x % T_NNZ;
      sidx[y][j] = cat[((size_t)t * T_BATCH + b0 + y) * T_NNZ + j];
    }
    __syncthreads();
    const f32x4* tb = (const f32x4*)(tables + (size_t)t * T_NUM_ROWS * T_WIDTH);
    f32x4 acc = {0.f, 0.f, 0.f, 0.f};
#pragma unroll
    for (int j = 0; j < T_NNZ; ++j) acc += tb[(size_t)sidx[ty][j] * 32 + tx];
    ushort4 u;
    {
      __hip_bfloat16 h0 = __float2bfloat16(acc[0]), h1 = __float2bfloat16(acc[1]);
      __hip_bfloat16 h2 = __float2bfloat16(acc[2]), h3 = __float2bfloat16(acc[3]);
      u.x = *(unsigned short*)&h0; u.y = *(unsigned short*)&h1;
      u.z = *(unsigned short*)&h2; u.w = *(unsigned short*)&h3;
    }
    *(ushort4*)(&xh[(size_t)(b0 + ty) * T_DE + t * T_WIDTH + tx * 4]) = u;
    return;
  }

  if (bid < PJ_WT) { // ---------------- weight transpose + bf16 cast
    int r = bid - PJ_POOL;
    const float* in;
    __hip_bfloat16* outt;
    int Kc, N, xb, yb;
    if (r < 1664)      { in = W1; outt = w1t; Kc = 3328; N = 512; xb = r % 104; yb = r / 104; }
    else if (r < 1792) { r -= 1664; in = W2; outt = w2t; Kc = 512; N = 256; xb = r % 16; yb = r / 16; }
    else               { r -= 1792; in = W3; outt = w3t; Kc = 256; N = 128; xb = r % 8;  yb = r / 8;  }
    int tx = threadIdx.x & 31, ty = threadIdx.x >> 5;
    int kb = xb * 32, nb = yb * 32;
    for (int rr = ty; rr < 32; rr += 8) tile[rr][tx] = in[(size_t)(kb + rr) * N + nb + tx];
    __syncthreads();
    for (int rr = ty; rr < 32; rr += 8)
      outt[(size_t)(nb + rr) * Kc + kb + tx] = __float2bfloat16(tile[tx][rr]);
    return;
  }

  { // ---------------- numerical bias (exact fp32) + out init
    int b = bid - PJ_WT;
    if (threadIdx.x < T_NUM_NUM) snum[threadIdx.x] = num[b * T_NUM_NUM + threadIdx.x];
    if (threadIdx.x == 0) out[b] = b4[0];
    __syncthreads();
#pragma unroll
    for (int rep = 0; rep < 2; ++rep) {
      int n = threadIdx.x + rep * 256;
      float acc = b1[n];
#pragma unroll
      for (int j = 0; j < T_NUM_NUM; ++j)
        acc += snum[j] * W1[(size_t)(T_DE + j) * 512 + n];
      c0[(size_t)b * 512 + n] = acc;
    }
  }
}

// ================= bf16 MFMA GEMM, depth-3 counted-vmcnt pipeline (T3/T4/T5) =================
// 4 waves 2x2; per-wave (BM/2)x(BN/2); 16x16x32 frags.
// 3 LDS buffers; steady-state wait = vmcnt(2L): two tiles' loads stay in flight.
template <int BM, int BN, int RELU, int MODE>
__global__ __launch_bounds__(256, 2) void gemm_v10(
    const __hip_bfloat16* __restrict__ A,   // [M][Kp]
    const __hip_bfloat16* __restrict__ Bt,  // [N][Kp]
    const float* __restrict__ bias1,        // [N] or null
    const float* __restrict__ bias2d,       // [M][N] or null
    const float* __restrict__ W4,           // MODE 2
    __hip_bfloat16* __restrict__ Ch,        // MODE 0
    float* __restrict__ outv,               // MODE 2
    int M, int N, int Kp) {
  constexpr int MR = BM / 32, NR = BN / 32;
  constexpr int BUFB = BM * 128 + BN * 128;
  constexpr int L = BM / 32 + BN / 32; // global_load_lds per wave per tile
  __shared__ char smem[3 * BUFB];

  const int tid = threadIdx.x;
  const int wave = tid >> 6;
  const int lane = tid & 63;
  const int m0 = blockIdx.x * BM;
  const int n0 = blockIdx.y * BN;
  const int wr = wave >> 1;
  const int wc = wave & 1;

  f32x4 acc[MR][NR] = {};
  const size_t strideA = (size_t)Kp * 2;

  auto stage = [&](int k0, int buf) {
    char* As = smem + buf * BUFB;
    char* Bs = As + BM * 128;
#pragma unroll
    for (int it = 0; it < BM / 32; ++it) {
      int chunk = wave + it * 4;
      int p = chunk * 1024 + lane * 16;
      int row = p >> 7, colb = p & 127;
      int colb_g = colb ^ ((row & 7) << 4); // inverse-swizzle SOURCE
      size_t goff = (size_t)(m0 + row) * strideA + (size_t)k0 * 2 + colb_g;
      __builtin_amdgcn_global_load_lds(
          (const __attribute__((address_space(1))) void*)((const char*)A + goff),
          (__attribute__((address_space(3))) void*)(As + chunk * 1024), 16, 0, 0);
    }
#pragma unroll
    for (int it = 0; it < BN / 32; ++it) {
      int chunk = wave + it * 4;
      int p = chunk * 1024 + lane * 16;
      int row = p >> 7, colb = p & 127;
      int colb_g = colb ^ ((row & 7) << 4);
      size_t goff = (size_t)(n0 + row) * strideA + (size_t)k0 * 2 + colb_g;
      __builtin_amdgcn_global_load_lds(
          (const __attribute__((address_space(1))) void*)((const char*)Bt + goff),
          (__attribute__((address_space(3))) void*)(Bs + chunk * 1024), 16, 0, 0);
    }
  };

  const int nt = Kp >> 6;
  stage(0, 0);
  if (nt > 1) stage(64, 1);
  if (nt > 2) stage(128, 2);
  int cur = 0;
  for (int t = 0; t < nt; ++t) {
    // in-order vmcnt: allow the prefetched tiles' loads to stay in flight
    if (t + 2 < nt) {
      asm volatile("s_waitcnt vmcnt(%0)" ::"n"(2 * L) : "memory");
    } else if (t + 1 < nt) {
      asm volatile("s_waitcnt vmcnt(%0)" ::"n"(L) : "memory");
    } else {
      asm volatile("s_waitcnt vmcnt(0)" ::: "memory");
    }
    __builtin_amdgcn_sched_barrier(0);
    __builtin_amdgcn_s_barrier(); // buf[cur] ready for all waves
    __builtin_amdgcn_sched_barrier(0);

    char* As = smem + cur * BUFB;
    char* Bs = As + BM * 128;
#pragma unroll
    for (int ks = 0; ks < 2; ++ks) {
      bf16x8 af[MR], bfr[NR];
      const int cb = (ks * 32 + ((lane >> 4) * 8)) * 2;
#pragma unroll
      for (int m = 0; m < MR; ++m) {
        int row = wr * (BM / 2) + m * 16 + (lane & 15);
        int addr = row * 128 + (cb ^ ((row & 7) << 4));
        af[m] = *(const bf16x8*)(As + addr);
      }
#pragma unroll
      for (int n = 0; n < NR; ++n) {
        int row = wc * (BN / 2) + n * 16 + (lane & 15);
        int addr = row * 128 + (cb ^ ((row & 7) << 4));
        bfr[n] = *(const bf16x8*)(Bs + addr);
      }
      __builtin_amdgcn_s_setprio(1);
#pragma unroll
      for (int m = 0; m < MR; ++m)
#pragma unroll
        for (int n = 0; n < NR; ++n)
          acc[m][n] = __builtin_amdgcn_mfma_f32_16x16x32_bf16(af[m], bfr[n], acc[m][n], 0, 0, 0);
      __builtin_amdgcn_s_setprio(0);
    }

    __builtin_amdgcn_sched_barrier(0);
    __builtin_amdgcn_s_barrier(); // all waves done reading buf[cur]
    __builtin_amdgcn_sched_barrier(0);
    if (t + 3 < nt) stage((t + 3) << 6, cur); // refill the buffer just freed
    cur = (cur == 2) ? 0 : cur + 1;
  }

  // epilogue: C/D layout col=lane&15, row=(lane>>4)*4+i
#pragma unroll
  for (int m = 0; m < MR; ++m) {
#pragma unroll
    for (int n = 0; n < NR; ++n) {
      int col = n0 + wc * (BN / 2) + n * 16 + (lane & 15);
      float bv = bias1 ? bias1[col] : 0.f;
      float w4c = (MODE == 2) ? W4[col] : 0.f;
      float dot[4];
#pragma unroll
      for (int i = 0; i < 4; ++i) {
        int row = m0 + wr * (BM / 2) + m * 16 + ((lane >> 4) * 4) + i;
        float v = acc[m][n][i] + bv;
        if (bias2d) v += bias2d[(size_t)row * N + col];
        if (RELU) v = fmaxf(v, 0.f);
        if (MODE == 0) {
          Ch[(size_t)row * N + col] = __float2bfloat16(v);
        } else {
          dot[i] = v * w4c;
        }
      }
      if (MODE == 2) {
#pragma unroll
        for (int i = 0; i < 4; ++i) {
#pragma unroll
          for (int mask = 1; mask < 16; mask <<= 1) dot[i] += __shfl_xor(dot[i], mask);
        }
        if ((lane & 15) == 0) {
          int rowb = m0 + wr * (BM / 2) + m * 16 + ((lane >> 4) * 4);
#pragma unroll
          for (int i = 0; i < 4; ++i) atomicAdd(&outv[rowb + i], dot[i]);
        }
      }
    }
  }
}

extern "C" void kernel_launch(void* const* d_in, const int* in_sizes, int n_in,
                              void* d_out, int out_size, void* d_ws, size_t ws_size,
                              hipStream_t stream) {
  const float* numerical = (const float*)d_in[0];
  const int* cat = (const int*)d_in[1];
  const float* tables = (const float*)d_in[2];
  const float* W1 = (const float*)d_in[3];
  const float* b1 = (const float*)d_in[4];
  const float* W2 = (const float*)d_in[5];
  const float* b2 = (const float*)d_in[6];
  const float* W3 = (const float*)d_in[7];
  const float* b3 = (const float*)d_in[8];
  const float* W4 = (const float*)d_in[9];
  const float* b4 = (const float*)d_in[10];
  float* out = (float*)d_out;

  char* ws = (char*)d_ws;
  size_t off = 0;
  auto walloc = [&](size_t bytes) -> void* {
    void* p = ws + off;
    off = (off + bytes + 255) & ~(size_t)255;
    return p;
  };
  __hip_bfloat16* xh  = (__hip_bfloat16*)walloc((size_t)T_BATCH * T_DE * 2);
  __hip_bfloat16* w1t = (__hip_bfloat16*)walloc((size_t)512 * T_DE * 2);
  float*          c0  = (float*)walloc((size_t)T_BATCH * 512 * 4);
  __hip_bfloat16* a1  = (__hip_bfloat16*)walloc((size_t)T_BATCH * 512 * 2);
  __hip_bfloat16* w2t = (__hip_bfloat16*)walloc((size_t)256 * 512 * 2);
  __hip_bfloat16* a2  = (__hip_bfloat16*)walloc((size_t)T_BATCH * 256 * 2);
  __hip_bfloat16* w3t = (__hip_bfloat16*)walloc((size_t)128 * 256 * 2);

  poolprep_v10<<<PJ_TOTAL, 256, 0, stream>>>(tables, cat, W1, W2, W3, b1, b4, numerical,
                                             xh, w1t, w2t, w3t, c0, out);

  gemm_v10<64, 64, 1, 0><<<dim3(T_BATCH / 64, 512 / 64), 256, 0, stream>>>(
      xh, w1t, nullptr, c0, nullptr, a1, nullptr, T_BATCH, 512, T_DE);
  gemm_v10<64, 64, 1, 0><<<dim3(T_BATCH / 64, 256 / 64), 256, 0, stream>>>(
      a1, w2t, b2, nullptr, nullptr, a2, nullptr, T_BATCH, 256, 512);
  gemm_v10<64, 32, 1, 2><<<dim3(T_BATCH / 64, 128 / 32), 256, 0, stream>>>(
      a2, w3t, b3, nullptr, W4, nullptr, out, T_BATCH, 128, 256);
}

// Round 11
// 195.276 us; speedup vs baseline: 1.0047x; 1.0047x over previous
//
#include <hip/hip_runtime.h>
#include <hip/hip_bf16.h>

#define T_NUM_TABLES 26
#define T_NUM_ROWS 50000
#define T_WIDTH 128
#define T_BATCH 4096
#define T_NNZ 20
#define T_NUM_NUM 13
#define T_DE (T_NUM_TABLES * T_WIDTH) /* 3328 = 64*52 */

typedef __attribute__((ext_vector_type(4))) float f32x4;
typedef __attribute__((ext_vector_type(8))) short bf16x8;

// ================= fused pool + prep =================
#define PJ_POOL (512 * T_NUM_TABLES)         /* 13312 */
#define PJ_WT (PJ_POOL + 1664 + 128 + 32)    /* 15136 */
#define PJ_TOTAL (PJ_WT + T_BATCH)           /* 19232 */

__global__ void poolprep_v11(const float* __restrict__ tables,
                             const int* __restrict__ cat,
                             const float* __restrict__ W1, const float* __restrict__ W2,
                             const float* __restrict__ W3, const float* __restrict__ b1,
                             const float* __restrict__ b4, const float* __restrict__ num,
                             __hip_bfloat16* __restrict__ xh,
                             __hip_bfloat16* __restrict__ w1t, __hip_bfloat16* __restrict__ w2t,
                             __hip_bfloat16* __restrict__ w3t, float* __restrict__ c0,
                             float* __restrict__ out) {
  __shared__ int sidx[8][T_NNZ];
  __shared__ float tile[32][33];
  __shared__ float snum[T_NUM_NUM];
  const int bid = blockIdx.x;

  if (bid < PJ_POOL) { // ---------------- pool: float4 gathers, table-major
    const int g = bid & 511;
    const int t = bid >> 9;
    const int b0 = g * 8;
    const int tx = threadIdx.x & 31;
    const int ty = threadIdx.x >> 5;
    if (threadIdx.x < 8 * T_NNZ) {
      int y = threadIdx.x / T_NNZ, j = threadIdx.x % T_NNZ;
      sidx[y][j] = cat[((size_t)t * T_BATCH + b0 + y) * T_NNZ + j];
    }
    __syncthreads();
    const f32x4* tb = (const f32x4*)(tables + (size_t)t * T_NUM_ROWS * T_WIDTH);
    f32x4 acc = {0.f, 0.f, 0.f, 0.f};
#pragma unroll
    for (int j = 0; j < T_NNZ; ++j) acc += tb[(size_t)sidx[ty][j] * 32 + tx];
    ushort4 u;
    {
      __hip_bfloat16 h0 = __float2bfloat16(acc[0]), h1 = __float2bfloat16(acc[1]);
      __hip_bfloat16 h2 = __float2bfloat16(acc[2]), h3 = __float2bfloat16(acc[3]);
      u.x = *(unsigned short*)&h0; u.y = *(unsigned short*)&h1;
      u.z = *(unsigned short*)&h2; u.w = *(unsigned short*)&h3;
    }
    *(ushort4*)(&xh[(size_t)(b0 + ty) * T_DE + t * T_WIDTH + tx * 4]) = u;
    return;
  }

  if (bid < PJ_WT) { // ---------------- weight transpose + bf16 cast
    int r = bid - PJ_POOL;
    const float* in;
    __hip_bfloat16* outt;
    int Kc, N, xb, yb;
    if (r < 1664)      { in = W1; outt = w1t; Kc = 3328; N = 512; xb = r % 104; yb = r / 104; }
    else if (r < 1792) { r -= 1664; in = W2; outt = w2t; Kc = 512; N = 256; xb = r % 16; yb = r / 16; }
    else               { r -= 1792; in = W3; outt = w3t; Kc = 256; N = 128; xb = r % 8;  yb = r / 8;  }
    int tx = threadIdx.x & 31, ty = threadIdx.x >> 5;
    int kb = xb * 32, nb = yb * 32;
    for (int rr = ty; rr < 32; rr += 8) tile[rr][tx] = in[(size_t)(kb + rr) * N + nb + tx];
    __syncthreads();
    for (int rr = ty; rr < 32; rr += 8)
      outt[(size_t)(nb + rr) * Kc + kb + tx] = __float2bfloat16(tile[tx][rr]);
    return;
  }

  { // ---------------- numerical bias (exact fp32) + out init
    int b = bid - PJ_WT;
    if (threadIdx.x < T_NUM_NUM) snum[threadIdx.x] = num[b * T_NUM_NUM + threadIdx.x];
    if (threadIdx.x == 0) out[b] = b4[0];
    __syncthreads();
#pragma unroll
    for (int rep = 0; rep < 2; ++rep) {
      int n = threadIdx.x + rep * 256;
      float acc = b1[n];
#pragma unroll
      for (int j = 0; j < T_NUM_NUM; ++j)
        acc += snum[j] * W1[(size_t)(T_DE + j) * 512 + n];
      c0[(size_t)b * 512 + n] = acc;
    }
  }
}

// ================= bf16 MFMA GEMM, depth-3 counted-vmcnt pipeline (T3/T4/T5) =================
// 4 waves 2x2; per-wave (BM/2)x(BN/2); 16x16x32 frags.
// 3 LDS buffers; steady-state wait = vmcnt(2L): two tiles' loads stay in flight.
template <int BM, int BN, int RELU, int MODE>
__global__ __launch_bounds__(256, 2) void gemm_v11(
    const __hip_bfloat16* __restrict__ A,   // [M][Kp]
    const __hip_bfloat16* __restrict__ Bt,  // [N][Kp]
    const float* __restrict__ bias1,        // [N] or null
    const float* __restrict__ bias2d,       // [M][N] or null
    const float* __restrict__ W4,           // MODE 2
    __hip_bfloat16* __restrict__ Ch,        // MODE 0
    float* __restrict__ outv,               // MODE 2
    int M, int N, int Kp) {
  constexpr int MR = BM / 32, NR = BN / 32;
  constexpr int BUFB = BM * 128 + BN * 128;
  constexpr int L = BM / 32 + BN / 32; // global_load_lds per wave per tile
  __shared__ char smem[3 * BUFB];

  const int tid = threadIdx.x;
  const int wave = tid >> 6;
  const int lane = tid & 63;
  const int m0 = blockIdx.x * BM;
  const int n0 = blockIdx.y * BN;
  const int wr = wave >> 1;
  const int wc = wave & 1;

  f32x4 acc[MR][NR] = {};
  const size_t strideA = (size_t)Kp * 2;

  auto stage = [&](int k0, int buf) {
    char* As = smem + buf * BUFB;
    char* Bs = As + BM * 128;
#pragma unroll
    for (int it = 0; it < BM / 32; ++it) {
      int chunk = wave + it * 4;
      int p = chunk * 1024 + lane * 16;
      int row = p >> 7, colb = p & 127;
      int colb_g = colb ^ ((row & 7) << 4); // inverse-swizzle SOURCE
      size_t goff = (size_t)(m0 + row) * strideA + (size_t)k0 * 2 + colb_g;
      __builtin_amdgcn_global_load_lds(
          (const __attribute__((address_space(1))) void*)((const char*)A + goff),
          (__attribute__((address_space(3))) void*)(As + chunk * 1024), 16, 0, 0);
    }
#pragma unroll
    for (int it = 0; it < BN / 32; ++it) {
      int chunk = wave + it * 4;
      int p = chunk * 1024 + lane * 16;
      int row = p >> 7, colb = p & 127;
      int colb_g = colb ^ ((row & 7) << 4);
      size_t goff = (size_t)(n0 + row) * strideA + (size_t)k0 * 2 + colb_g;
      __builtin_amdgcn_global_load_lds(
          (const __attribute__((address_space(1))) void*)((const char*)Bt + goff),
          (__attribute__((address_space(3))) void*)(Bs + chunk * 1024), 16, 0, 0);
    }
  };

  const int nt = Kp >> 6;
  stage(0, 0);
  if (nt > 1) stage(64, 1);
  if (nt > 2) stage(128, 2);
  int cur = 0;
  for (int t = 0; t < nt; ++t) {
    // in-order vmcnt: allow the prefetched tiles' loads to stay in flight
    if (t + 2 < nt) {
      asm volatile("s_waitcnt vmcnt(%0)" ::"n"(2 * L) : "memory");
    } else if (t + 1 < nt) {
      asm volatile("s_waitcnt vmcnt(%0)" ::"n"(L) : "memory");
    } else {
      asm volatile("s_waitcnt vmcnt(0)" ::: "memory");
    }
    __builtin_amdgcn_sched_barrier(0);
    __builtin_amdgcn_s_barrier(); // buf[cur] ready for all waves
    __builtin_amdgcn_sched_barrier(0);

    char* As = smem + cur * BUFB;
    char* Bs = As + BM * 128;
#pragma unroll
    for (int ks = 0; ks < 2; ++ks) {
      bf16x8 af[MR], bfr[NR];
      const int cb = (ks * 32 + ((lane >> 4) * 8)) * 2;
#pragma unroll
      for (int m = 0; m < MR; ++m) {
        int row = wr * (BM / 2) + m * 16 + (lane & 15);
        int addr = row * 128 + (cb ^ ((row & 7) << 4));
        af[m] = *(const bf16x8*)(As + addr);
      }
#pragma unroll
      for (int n = 0; n < NR; ++n) {
        int row = wc * (BN / 2) + n * 16 + (lane & 15);
        int addr = row * 128 + (cb ^ ((row & 7) << 4));
        bfr[n] = *(const bf16x8*)(Bs + addr);
      }
      __builtin_amdgcn_s_setprio(1);
#pragma unroll
      for (int m = 0; m < MR; ++m)
#pragma unroll
        for (int n = 0; n < NR; ++n)
          acc[m][n] = __builtin_amdgcn_mfma_f32_16x16x32_bf16(af[m], bfr[n], acc[m][n], 0, 0, 0);
      __builtin_amdgcn_s_setprio(0);
    }

    __builtin_amdgcn_sched_barrier(0);
    __builtin_amdgcn_s_barrier(); // all waves done reading buf[cur]
    __builtin_amdgcn_sched_barrier(0);
    if (t + 3 < nt) stage((t + 3) << 6, cur); // refill the buffer just freed
    cur = (cur == 2) ? 0 : cur + 1;
  }

  // epilogue: C/D layout col=lane&15, row=(lane>>4)*4+i
#pragma unroll
  for (int m = 0; m < MR; ++m) {
#pragma unroll
    for (int n = 0; n < NR; ++n) {
      int col = n0 + wc * (BN / 2) + n * 16 + (lane & 15);
      float bv = bias1 ? bias1[col] : 0.f;
      float w4c = (MODE == 2) ? W4[col] : 0.f;
      float dot[4];
#pragma unroll
      for (int i = 0; i < 4; ++i) {
        int row = m0 + wr * (BM / 2) + m * 16 + ((lane >> 4) * 4) + i;
        float v = acc[m][n][i] + bv;
        if (bias2d) v += bias2d[(size_t)row * N + col];
        if (RELU) v = fmaxf(v, 0.f);
        if (MODE == 0) {
          Ch[(size_t)row * N + col] = __float2bfloat16(v);
        } else {
          dot[i] = v * w4c;
        }
      }
      if (MODE == 2) {
#pragma unroll
        for (int i = 0; i < 4; ++i) {
#pragma unroll
          for (int mask = 1; mask < 16; mask <<= 1) dot[i] += __shfl_xor(dot[i], mask);
        }
        if ((lane & 15) == 0) {
          int rowb = m0 + wr * (BM / 2) + m * 16 + ((lane >> 4) * 4);
#pragma unroll
          for (int i = 0; i < 4; ++i) atomicAdd(&outv[rowb + i], dot[i]);
        }
      }
    }
  }
}

extern "C" void kernel_launch(void* const* d_in, const int* in_sizes, int n_in,
                              void* d_out, int out_size, void* d_ws, size_t ws_size,
                              hipStream_t stream) {
  const float* numerical = (const float*)d_in[0];
  const int* cat = (const int*)d_in[1];
  const float* tables = (const float*)d_in[2];
  const float* W1 = (const float*)d_in[3];
  const float* b1 = (const float*)d_in[4];
  const float* W2 = (const float*)d_in[5];
  const float* b2 = (const float*)d_in[6];
  const float* W3 = (const float*)d_in[7];
  const float* b3 = (const float*)d_in[8];
  const float* W4 = (const float*)d_in[9];
  const float* b4 = (const float*)d_in[10];
  float* out = (float*)d_out;

  char* ws = (char*)d_ws;
  size_t off = 0;
  auto walloc = [&](size_t bytes) -> void* {
    void* p = ws + off;
    off = (off + bytes + 255) & ~(size_t)255;
    return p;
  };
  __hip_bfloat16* xh  = (__hip_bfloat16*)walloc((size_t)T_BATCH * T_DE * 2);
  __hip_bfloat16* w1t = (__hip_bfloat16*)walloc((size_t)512 * T_DE * 2);
  float*          c0  = (float*)walloc((size_t)T_BATCH * 512 * 4);
  __hip_bfloat16* a1  = (__hip_bfloat16*)walloc((size_t)T_BATCH * 512 * 2);
  __hip_bfloat16* w2t = (__hip_bfloat16*)walloc((size_t)256 * 512 * 2);
  __hip_bfloat16* a2  = (__hip_bfloat16*)walloc((size_t)T_BATCH * 256 * 2);
  __hip_bfloat16* w3t = (__hip_bfloat16*)walloc((size_t)128 * 256 * 2);

  poolprep_v11<<<PJ_TOTAL, 256, 0, stream>>>(tables, cat, W1, W2, W3, b1, b4, numerical,
                                             xh, w1t, w2t, w3t, c0, out);

  // gemm1: 64x64, 512 blocks = 2/CU (measured-best)
  gemm_v11<64, 64, 1, 0><<<dim3(T_BATCH / 64, 512 / 64), 256, 0, stream>>>(
      xh, w1t, nullptr, c0, nullptr, a1, nullptr, T_BATCH, 512, T_DE);
  // gemm2: 64x32 -> grid (64,8)=512 blocks = 2/CU (was 256 = 1/CU)
  gemm_v11<64, 32, 1, 0><<<dim3(T_BATCH / 64, 256 / 32), 256, 0, stream>>>(
      a1, w2t, b2, nullptr, nullptr, a2, nullptr, T_BATCH, 256, 512);
  // gemm3: 32x32 -> grid (128,4)=512 blocks = 2/CU (was 256 = 1/CU)
  gemm_v11<32, 32, 1, 2><<<dim3(T_BATCH / 32, 128 / 32), 256, 0, stream>>>(
      a2, w3t, b3, nullptr, W4, nullptr, out, T_BATCH, 128, 256);
}